// Round 12
// baseline (120.365 us; speedup 1.0000x reference)
//
#include <hip/hip_runtime.h>
#include <math.h>

#define NS 4
#define SINKHORN_ITERS 10
#define TAU 0.05f

// T*D/4 in float4 units: 4096*2048/4 = 2^21
#define PLANE4 2097152L
#define PLANE4_SHIFT 21
#define NTHREADS (1 << 20)   // 4096 blocks x 256 threads

typedef float f32x4 __attribute__((ext_vector_type(4)));

// ---------------------------------------------------------------------------
// Serial coefficient math (one lane): M[so][si] = Hres[si][so] + ho[so]*hp[si]
// ---------------------------------------------------------------------------
__device__ void compute_M_serial(const float* __restrict__ Hres_logits,
                                 const float* __restrict__ Hpre_logits,
                                 const float* __restrict__ Hpost_logits,
                                 float* __restrict__ m /*[16]*/) {
    float Z[NS][NS], u[NS], v[NS];
    for (int i = 0; i < NS; ++i)
        for (int j = 0; j < NS; ++j)
            Z[i][j] = Hres_logits[i * NS + j] / TAU;

    const float logm = -logf((float)NS);
    for (int i = 0; i < NS; ++i) { u[i] = 0.f; v[i] = 0.f; }

    for (int it = 0; it < SINKHORN_ITERS; ++it) {
        for (int i = 0; i < NS; ++i) {
            float mx = -INFINITY;
            for (int j = 0; j < NS; ++j) mx = fmaxf(mx, Z[i][j] + v[j]);
            float s = 0.f;
            for (int j = 0; j < NS; ++j) s += expf(Z[i][j] + v[j] - mx);
            u[i] = logm - (mx + logf(s));
        }
        for (int j = 0; j < NS; ++j) {
            float mx = -INFINITY;
            for (int i = 0; i < NS; ++i) mx = fmaxf(mx, Z[i][j] + u[i]);
            float s = 0.f;
            for (int i = 0; i < NS; ++i) s += expf(Z[i][j] + u[i] - mx);
            v[j] = logm - (mx + logf(s));
        }
    }

    float hp[NS], mx = -INFINITY, s = 0.f;
    for (int i = 0; i < NS; ++i) mx = fmaxf(mx, Hpre_logits[i]);
    for (int i = 0; i < NS; ++i) { hp[i] = expf(Hpre_logits[i] - mx); s += hp[i]; }
    for (int i = 0; i < NS; ++i) hp[i] /= s;

    float ho[NS];
    mx = -INFINITY; s = 0.f;
    for (int i = 0; i < NS; ++i) mx = fmaxf(mx, Hpost_logits[i]);
    for (int i = 0; i < NS; ++i) { ho[i] = expf(Hpost_logits[i] - mx); s += ho[i]; }
    for (int i = 0; i < NS; ++i) ho[i] /= s;

    for (int so = 0; so < NS; ++so)
        for (int si = 0; si < NS; ++si)
            m[so * NS + si] = expf(Z[si][so] + u[si] + v[so]) * (float)NS
                              + ho[so] * hp[si];
}

// ---------------------------------------------------------------------------
// Fused kernel (fast path): R10 memory structure (block-contiguous remap,
// plain loads, NT stores). Each thread issues its 16 loads; thread 0 of the
// block computes M into LDS while those loads are in flight (the barrier's
// implicit vmcnt-wait overlaps the ~1-2us Sinkhorn chain); then FMA+store.
// ---------------------------------------------------------------------------
__global__ __launch_bounds__(256) void hc_fused(
        const f32x4* __restrict__ in,
        const float* __restrict__ Hres_logits,
        const float* __restrict__ Hpre_logits,
        const float* __restrict__ Hpost_logits,
        f32x4* __restrict__ out) {
    __shared__ float Msh[16];

    const long bb   = blockIdx.x >> 11;                       // batch (0..1), uniform
    const long q    = ((long)(blockIdx.x & 2047) << 10) + threadIdx.x;
    const long base = bb * (NS * PLANE4) + q;                 // + s*PLANE4 + k*256

    f32x4 v[4][NS];
#pragma unroll
    for (int k = 0; k < 4; ++k)
#pragma unroll
        for (int s = 0; s < NS; ++s)
            v[k][s] = in[base + (long)s * PLANE4 + k * 256];

    if (threadIdx.x == 0) {
        float m[16];
        compute_M_serial(Hres_logits, Hpre_logits, Hpost_logits, m);
        for (int k = 0; k < 16; ++k) Msh[k] = m[k];
    }
    __syncthreads();

    float m[16];
#pragma unroll
    for (int k = 0; k < 16; ++k) m[k] = Msh[k];

#pragma unroll
    for (int k = 0; k < 4; ++k)
#pragma unroll
        for (int o = 0; o < NS; ++o) {
            f32x4 r = m[o*4+0] * v[k][0] + m[o*4+1] * v[k][1] +
                      m[o*4+2] * v[k][2] + m[o*4+3] * v[k][3];
            __builtin_nontemporal_store(r, &out[base + (long)o * PLANE4 + k * 256]);
        }
}

// ---------------------------------------------------------------------------
// Generic fallback path (any size): two kernels as before.
// ---------------------------------------------------------------------------
__global__ void hc_coef_kernel(const float* __restrict__ Hres_logits,
                               const float* __restrict__ Hpre_logits,
                               const float* __restrict__ Hpost_logits,
                               float* __restrict__ M) {
    if (threadIdx.x != 0 || blockIdx.x != 0) return;
    float m[16];
    compute_M_serial(Hres_logits, Hpre_logits, Hpost_logits, m);
    for (int k = 0; k < 16; ++k) M[k] = m[k];
}

__global__ __launch_bounds__(256) void hc_mix_generic(
        const f32x4* __restrict__ in,
        const float* __restrict__ Mg,
        f32x4* __restrict__ out,
        int npos4) {
    float m[16];
#pragma unroll
    for (int k = 0; k < 16; ++k) m[k] = Mg[k];

    const int stride = gridDim.x * blockDim.x;
    for (int p = blockIdx.x * blockDim.x + threadIdx.x; p < npos4; p += stride) {
        const int b = p >> PLANE4_SHIFT;
        const long base = ((long)(b * NS) << PLANE4_SHIFT) + (p & (PLANE4 - 1));
        const f32x4 v0 = in[base];
        const f32x4 v1 = in[base + PLANE4];
        const f32x4 v2 = in[base + 2 * PLANE4];
        const f32x4 v3 = in[base + 3 * PLANE4];
#pragma unroll
        for (int o = 0; o < NS; ++o) {
            f32x4 r = m[o*4+0]*v0 + m[o*4+1]*v1 + m[o*4+2]*v2 + m[o*4+3]*v3;
            __builtin_nontemporal_store(r, &out[base + (long)o * PLANE4]);
        }
    }
}

extern "C" void kernel_launch(void* const* d_in, const int* in_sizes, int n_in,
                              void* d_out, int out_size, void* d_ws, size_t ws_size,
                              hipStream_t stream) {
    const float* residuals   = (const float*)d_in[0];  // (B*S, T, D) = (8,4096,2048) f32
    const float* Hres_logits = (const float*)d_in[1];  // (4,4)
    const float* Hpre_logits = (const float*)d_in[2];  // (4,)
    const float* Hpost_logits= (const float*)d_in[3];  // (4,)
    float* out = (float*)d_out;
    float* M   = (float*)d_ws;                         // 16 floats

    const int npos4 = out_size / (NS * 4);             // B*T*D/4 = 4194304
    if (npos4 == 4 * NTHREADS) {
        hc_fused<<<NTHREADS / 256, 256, 0, stream>>>(
            (const f32x4*)residuals, Hres_logits, Hpre_logits, Hpost_logits,
            (f32x4*)out);
    } else {
        hc_coef_kernel<<<1, 64, 0, stream>>>(Hres_logits, Hpre_logits, Hpost_logits, M);
        hc_mix_generic<<<2048, 256, 0, stream>>>(
            (const f32x4*)residuals, M, (f32x4*)out, npos4);
    }
}

// Round 13
// 83.969 us; speedup vs baseline: 1.4334x; 1.4334x over previous
//
#include <hip/hip_runtime.h>
#include <math.h>

#define NS 4
#define SINKHORN_ITERS 10
#define TAU 0.05f

// T*D/4 in float4 units: 4096*2048/4 = 2^21
#define PLANE4 2097152L
#define PLANE4_SHIFT 21
#define NTHREADS (1 << 20)   // 4096 blocks x 256 threads

typedef float f32x4 __attribute__((ext_vector_type(4)));

// ---------------------------------------------------------------------------
// Wave-parallel coefficient math. Lane L maps to (i,j) = ((L>>2)&3, L&3);
// every 16-lane group computes redundantly. Reductions over j: shfl_xor 1,2;
// over i: shfl_xor 4,8. Chain ~400 cycles (vs ~8k serial) — hides under the
// in-flight global loads. Returns m[16] (broadcast) with
// m[so*4+si] = Hres[si][so] + ho[so]*hp[si].
// ---------------------------------------------------------------------------
__device__ __forceinline__ void compute_M_wave(const float* __restrict__ Hres_logits,
                                               const float* __restrict__ Hpre_logits,
                                               const float* __restrict__ Hpost_logits,
                                               float* __restrict__ m /*[16]*/) {
    const int i = (threadIdx.x >> 2) & 3;
    const int j = threadIdx.x & 3;

    const float Zl = Hres_logits[i * NS + j] * (1.0f / TAU);
    const float logm = -logf((float)NS);
    float u_ = 0.f, v_ = 0.f;

    for (int it = 0; it < SINKHORN_ITERS; ++it) {
        // u[i] = logm - lse_j(Z[i][j] + v[j])
        float t  = Zl + v_;
        float mx = t;
        mx = fmaxf(mx, __shfl_xor(mx, 1));
        mx = fmaxf(mx, __shfl_xor(mx, 2));
        float e = expf(t - mx);
        float s = e;
        s += __shfl_xor(s, 1);
        s += __shfl_xor(s, 2);
        u_ = logm - (mx + logf(s));

        // v[j] = logm - lse_i(Z[i][j] + u[i])
        t  = Zl + u_;
        mx = t;
        mx = fmaxf(mx, __shfl_xor(mx, 4));
        mx = fmaxf(mx, __shfl_xor(mx, 8));
        e = expf(t - mx);
        s = e;
        s += __shfl_xor(s, 4);
        s += __shfl_xor(s, 8);
        v_ = logm - (mx + logf(s));
    }

    const float HresV = expf(Zl + u_ + v_) * (float)NS;   // Hres[i][j]

    // hp[i] = softmax(Hpre)[i]  (reduce over i: xor 4,8)
    float pre = Hpre_logits[i];
    float mx = pre;
    mx = fmaxf(mx, __shfl_xor(mx, 4));
    mx = fmaxf(mx, __shfl_xor(mx, 8));
    float e = expf(pre - mx);
    float s = e;
    s += __shfl_xor(s, 4);
    s += __shfl_xor(s, 8);
    const float hp_i = e / s;

    // ho[j] = softmax(Hpost)[j]  (reduce over j: xor 1,2)
    float post = Hpost_logits[j];
    mx = post;
    mx = fmaxf(mx, __shfl_xor(mx, 1));
    mx = fmaxf(mx, __shfl_xor(mx, 2));
    e = expf(post - mx);
    s = e;
    s += __shfl_xor(s, 1);
    s += __shfl_xor(s, 2);
    const float ho_j = e / s;

    // lane (i,j) holds M[so=j][si=i]
    const float Mval = HresV + ho_j * hp_i;

    // broadcast: m[so*4+si] lives at lane si*4+so (lanes 0..15 of the wave)
#pragma unroll
    for (int o = 0; o < NS; ++o)
#pragma unroll
        for (int si = 0; si < NS; ++si)
            m[o * NS + si] = __shfl(Mval, si * NS + o);
}

// ---------------------------------------------------------------------------
// Fused fast path: R10 memory structure (block-contiguous remap, plain loads,
// NT stores). Loads issue first; wave-parallel M computes in the load shadow.
// ---------------------------------------------------------------------------
__global__ __launch_bounds__(256) void hc_fused(
        const f32x4* __restrict__ in,
        const float* __restrict__ Hres_logits,
        const float* __restrict__ Hpre_logits,
        const float* __restrict__ Hpost_logits,
        f32x4* __restrict__ out) {
    const long bb   = blockIdx.x >> 11;                       // batch (0..1), uniform
    const long q    = ((long)(blockIdx.x & 2047) << 10) + threadIdx.x;
    const long base = bb * (NS * PLANE4) + q;                 // + s*PLANE4 + k*256

    f32x4 v[4][NS];
#pragma unroll
    for (int k = 0; k < 4; ++k)
#pragma unroll
        for (int s = 0; s < NS; ++s)
            v[k][s] = in[base + (long)s * PLANE4 + k * 256];

    float m[16];
    compute_M_wave(Hres_logits, Hpre_logits, Hpost_logits, m);

#pragma unroll
    for (int k = 0; k < 4; ++k)
#pragma unroll
        for (int o = 0; o < NS; ++o) {
            f32x4 r = m[o*4+0] * v[k][0] + m[o*4+1] * v[k][1] +
                      m[o*4+2] * v[k][2] + m[o*4+3] * v[k][3];
            __builtin_nontemporal_store(r, &out[base + (long)o * PLANE4 + k * 256]);
        }
}

// ---------------------------------------------------------------------------
// Generic fallback path (any size): fused too (wave-parallel M is cheap).
// ---------------------------------------------------------------------------
__global__ __launch_bounds__(256) void hc_mix_generic(
        const f32x4* __restrict__ in,
        const float* __restrict__ Hres_logits,
        const float* __restrict__ Hpre_logits,
        const float* __restrict__ Hpost_logits,
        f32x4* __restrict__ out,
        int npos4) {
    float m[16];
    compute_M_wave(Hres_logits, Hpre_logits, Hpost_logits, m);

    const int stride = gridDim.x * blockDim.x;
    for (int p = blockIdx.x * blockDim.x + threadIdx.x; p < npos4; p += stride) {
        const int b = p >> PLANE4_SHIFT;
        const long base = ((long)(b * NS) << PLANE4_SHIFT) + (p & (PLANE4 - 1));
        const f32x4 v0 = in[base];
        const f32x4 v1 = in[base + PLANE4];
        const f32x4 v2 = in[base + 2 * PLANE4];
        const f32x4 v3 = in[base + 3 * PLANE4];
#pragma unroll
        for (int o = 0; o < NS; ++o) {
            f32x4 r = m[o*4+0]*v0 + m[o*4+1]*v1 + m[o*4+2]*v2 + m[o*4+3]*v3;
            __builtin_nontemporal_store(r, &out[base + (long)o * PLANE4]);
        }
    }
}

extern "C" void kernel_launch(void* const* d_in, const int* in_sizes, int n_in,
                              void* d_out, int out_size, void* d_ws, size_t ws_size,
                              hipStream_t stream) {
    const float* residuals   = (const float*)d_in[0];  // (B*S, T, D) = (8,4096,2048) f32
    const float* Hres_logits = (const float*)d_in[1];  // (4,4)
    const float* Hpre_logits = (const float*)d_in[2];  // (4,)
    const float* Hpost_logits= (const float*)d_in[3];  // (4,)
    float* out = (float*)d_out;

    const int npos4 = out_size / (NS * 4);             // B*T*D/4 = 4194304
    if (npos4 == 4 * NTHREADS) {
        hc_fused<<<NTHREADS / 256, 256, 0, stream>>>(
            (const f32x4*)residuals, Hres_logits, Hpre_logits, Hpost_logits,
            (f32x4*)out);
    } else {
        hc_mix_generic<<<2048, 256, 0, stream>>>(
            (const f32x4*)residuals, Hres_logits, Hpre_logits, Hpost_logits,
            (f32x4*)out, npos4);
    }
}